// Round 1
// baseline (6537.447 us; speedup 1.0000x reference)
//
#include <hip/hip_runtime.h>

// Problem constants (B,C,H,W) = (4,96,128,256), decoder level 6.
constexpr int Bn  = 4;
constexpr int Cin = 96;
constexpr int Hh  = 128;
constexpr int Ww  = 256;
constexpr int HWn = Hh * Ww;          // 32768
constexpr int FC  = 433;              // final tenFeat channels
constexpr int FLOW_ELEMS = Bn * 2 * HWn;  // 262144 floats (output 0)

// ---------------------------------------------------------------------------
// Correlation: out[d][y][x] = lrelu( sum_c A[c,y,x] * B[c, y+dy, x+dx] ),
// d = (dy+4)*9 + (dx+4). Written to feat channels [352, 433).
// ---------------------------------------------------------------------------
__global__ __launch_bounds__(256) void corr_kernel(
    const float* __restrict__ A, const float* __restrict__ B2,
    float* __restrict__ feat)
{
    const int x = threadIdx.x;      // 0..255 = full row
    const int y = blockIdx.x;       // 0..127
    const int b = blockIdx.y;       // 0..3

    float acc[81];
#pragma unroll
    for (int d = 0; d < 81; ++d) acc[d] = 0.f;

    const float* ap = A + ((size_t)b * Cin) * HWn + y * Ww + x;
    const float* bp = B2 + ((size_t)b * Cin) * HWn;

    for (int c = 0; c < Cin; ++c) {
        const float av = ap[(size_t)c * HWn];
        const float* br = bp + (size_t)c * HWn;
#pragma unroll
        for (int dy = -4; dy <= 4; ++dy) {
            const int yy = y + dy;
            const bool yok = (unsigned)yy < (unsigned)Hh;   // block-uniform
#pragma unroll
            for (int dx = -4; dx <= 4; ++dx) {
                const int xx = x + dx;
                const float bv = (yok && (unsigned)xx < (unsigned)Ww)
                                     ? br[yy * Ww + xx] : 0.f;
                acc[(dy + 4) * 9 + (dx + 4)] =
                    fmaf(av, bv, acc[(dy + 4) * 9 + (dx + 4)]);
            }
        }
    }

    float* op = feat + ((size_t)b * FC + 352) * HWn + y * Ww + x;
#pragma unroll
    for (int d = 0; d < 81; ++d) {
        float v = acc[d];
        v = (v >= 0.f) ? v : 0.1f * v;
        op[(size_t)d * HWn] = v;
    }
}

// ---------------------------------------------------------------------------
// Generic 3x3 SAME conv + leaky-relu.
//   fin  = feat + ci_start*HW   (batch stride FC*HW, channel stride HW)
//   fout = feat + co_start*HW
//   Wt   = [CO][CI][3][3] (OIHW), bias = [CO]
// Thread = 1 pixel, COC output channels in registers; weights are
// wave-uniform -> scalar loads.
// ---------------------------------------------------------------------------
template <int CI, int COC>
__global__ __launch_bounds__(256) void conv_kernel(
    const float* __restrict__ fin, const float* __restrict__ Wt,
    const float* __restrict__ bias, float* __restrict__ fout)
{
    const int x  = threadIdx.x;
    const int y  = blockIdx.x;
    const int b  = blockIdx.y;
    const int co0 = blockIdx.z * COC;

    const float* in_b = fin + (size_t)b * FC * HWn;

    float acc[COC];
#pragma unroll
    for (int cc = 0; cc < COC; ++cc) acc[cc] = bias[co0 + cc];

    for (int ci = 0; ci < CI; ++ci) {
        const float* p = in_b + (size_t)ci * HWn;
        float v[9];
#pragma unroll
        for (int ky = 0; ky < 3; ++ky) {
            const int yy = y + ky - 1;
            const bool yok = (unsigned)yy < (unsigned)Hh;   // block-uniform
#pragma unroll
            for (int kx = 0; kx < 3; ++kx) {
                const int xx = x + kx - 1;
                v[ky * 3 + kx] = (yok && (unsigned)xx < (unsigned)Ww)
                                     ? p[yy * Ww + xx] : 0.f;
            }
        }
        const float* wp = Wt + ((size_t)co0 * CI + ci) * 9;
#pragma unroll
        for (int cc = 0; cc < COC; ++cc) {
#pragma unroll
            for (int t = 0; t < 9; ++t)
                acc[cc] = fmaf(wp[(size_t)cc * CI * 9 + t], v[t], acc[cc]);
        }
    }

    float* op = fout + ((size_t)b * FC + co0) * HWn + y * Ww + x;
#pragma unroll
    for (int cc = 0; cc < COC; ++cc) {
        float o = acc[cc];
        o = (o >= 0.f) ? o : 0.1f * o;
        op[(size_t)cc * HWn] = o;
    }
}

// ---------------------------------------------------------------------------
// Flow head: 433->81 conv (NO lrelu) fused with weighted-mean attention.
// Each block handles 9 of the 81 output channels for one row; partial
// (fx,fy) accumulated into flow via atomicAdd (flow pre-zeroed).
//   vx[d] = d%9 - 4, vy[d] = d/9 - 4, result = mean over 81.
// ---------------------------------------------------------------------------
__global__ __launch_bounds__(256) void flow_kernel(
    const float* __restrict__ fin, const float* __restrict__ Wt,
    const float* __restrict__ bias, float* __restrict__ flow)
{
    const int x  = threadIdx.x;
    const int y  = blockIdx.x;
    const int b  = blockIdx.y;
    const int co0 = blockIdx.z * 9;

    const float* in_b = fin + (size_t)b * FC * HWn;

    float acc[9];
#pragma unroll
    for (int j = 0; j < 9; ++j) acc[j] = bias[co0 + j];

    for (int ci = 0; ci < FC; ++ci) {
        const float* p = in_b + (size_t)ci * HWn;
        float v[9];
#pragma unroll
        for (int ky = 0; ky < 3; ++ky) {
            const int yy = y + ky - 1;
            const bool yok = (unsigned)yy < (unsigned)Hh;
#pragma unroll
            for (int kx = 0; kx < 3; ++kx) {
                const int xx = x + kx - 1;
                v[ky * 3 + kx] = (yok && (unsigned)xx < (unsigned)Ww)
                                     ? p[yy * Ww + xx] : 0.f;
            }
        }
        const float* wp = Wt + ((size_t)co0 * FC + ci) * 9;
#pragma unroll
        for (int j = 0; j < 9; ++j) {
#pragma unroll
            for (int t = 0; t < 9; ++t)
                acc[j] = fmaf(wp[(size_t)j * FC * 9 + t], v[t], acc[j]);
        }
    }

    float fx = 0.f, fy = 0.f;
#pragma unroll
    for (int j = 0; j < 9; ++j) {
        const int co = co0 + j;
        fx += acc[j] * (float)(co % 9 - 4);
        fy += acc[j] * (float)(co / 9 - 4);
    }

    float* o = flow + ((size_t)b * 2) * HWn + y * Ww + x;
    atomicAdd(o, fx * (1.f / 81.f));
    atomicAdd(o + HWn, fy * (1.f / 81.f));
}

// ---------------------------------------------------------------------------
// Launch. d_out = [flow: 4*2*128*256] ++ [feat: 4*433*128*256], fp32.
// tenFeat is built IN PLACE in d_out; channel layout (front to back):
//   [c5:0-31][c4:32-95][c3:96-159][c2:160-255][c1:256-351][vol:352-432]
// so every conv input is a contiguous channel suffix.
// ---------------------------------------------------------------------------
extern "C" void kernel_launch(void* const* d_in, const int* in_sizes, int n_in,
                              void* d_out, int out_size, void* d_ws, size_t ws_size,
                              hipStream_t stream)
{
    const float* tenFirst  = (const float*)d_in[0];
    const float* tenSecond = (const float*)d_in[1];
    const float* W1 = (const float*)d_in[2];   const float* b1 = (const float*)d_in[3];
    const float* W2 = (const float*)d_in[4];   const float* b2 = (const float*)d_in[5];
    const float* W3 = (const float*)d_in[6];   const float* b3 = (const float*)d_in[7];
    const float* W4 = (const float*)d_in[8];   const float* b4 = (const float*)d_in[9];
    const float* W5 = (const float*)d_in[10];  const float* b5 = (const float*)d_in[11];
    const float* Wf = (const float*)d_in[12];  const float* bf = (const float*)d_in[13];

    float* out  = (float*)d_out;
    float* feat = out + FLOW_ELEMS;

    // flow accumulated via atomics -> zero it first (graph-capturable)
    hipMemsetAsync(out, 0, FLOW_ELEMS * sizeof(float), stream);

    corr_kernel<<<dim3(Hh, Bn), 256, 0, stream>>>(tenFirst, tenSecond, feat);

    conv_kernel<81, 16><<<dim3(Hh, Bn, 6), 256, 0, stream>>>(
        feat + (size_t)352 * HWn, W1, b1, feat + (size_t)256 * HWn);
    conv_kernel<177, 16><<<dim3(Hh, Bn, 6), 256, 0, stream>>>(
        feat + (size_t)256 * HWn, W2, b2, feat + (size_t)160 * HWn);
    conv_kernel<273, 16><<<dim3(Hh, Bn, 4), 256, 0, stream>>>(
        feat + (size_t)160 * HWn, W3, b3, feat + (size_t)96 * HWn);
    conv_kernel<337, 16><<<dim3(Hh, Bn, 4), 256, 0, stream>>>(
        feat + (size_t)96 * HWn, W4, b4, feat + (size_t)32 * HWn);
    conv_kernel<401, 16><<<dim3(Hh, Bn, 2), 256, 0, stream>>>(
        feat + (size_t)32 * HWn, W5, b5, feat);

    flow_kernel<<<dim3(Hh, Bn, 9), 256, 0, stream>>>(feat, Wf, bf, out);
}

// Round 2
// 1864.793 us; speedup vs baseline: 3.5057x; 3.5057x over previous
//
#include <hip/hip_runtime.h>

// (B,C,H,W) = (4,96,128,256), level-6 decoder.
constexpr int Bn = 4, Hh = 128, Ww = 256, HWn = Hh * Ww;   // 32768
constexpr int FC = 433;
constexpr int FLOW_ELEMS = Bn * 2 * HWn;                    // 262144
// bf16 channel-minor shadow feat: [B][Hp][Wp][Cp], halos + channel pad zeroed
constexpr int Hp = 130, Wp = 258, Cp = 448;
constexpr size_t FB_BATCH = (size_t)Hp * Wp * Cp;           // 15,025,920
constexpr size_t FEATBF_ELEMS = (size_t)Bn * FB_BATCH;      // 60,103,680 (x2B = 120.2 MB)

using short8 = __attribute__((ext_vector_type(8))) short;   // 8 x bf16 (4 VGPRs)
using f32x4  = __attribute__((ext_vector_type(4))) float;

__device__ __forceinline__ unsigned short f2bf(float v) {
    union { float f; unsigned u; } x; x.f = v;
    unsigned r = x.u + 0x7fff + ((x.u >> 16) & 1);          // RNE
    return (unsigned short)(r >> 16);
}

// ---------------------------------------------------------------------------
// Weight pretransform: OIHW fp32 [CO][CI][3][3] -> bf16 [9][COP][CIP], zero-pad.
// ---------------------------------------------------------------------------
__global__ void wtrans(const float* __restrict__ src, unsigned short* __restrict__ dst,
                       int CO, int CI, int COP, int CIP)
{
    int idx = blockIdx.x * 256 + threadIdx.x;
    int total = 9 * COP * CIP;
    if (idx >= total) return;
    int t  = idx / (COP * CIP);
    int r  = idx % (COP * CIP);
    int co = r / CIP;
    int ci = r % CIP;
    float v = (co < CO && ci < CI) ? src[((size_t)co * CI + ci) * 9 + t] : 0.f;
    dst[idx] = f2bf(v);
}

// ---------------------------------------------------------------------------
// Correlation (fp32 direct) + lrelu; writes fp32 feat ch[352,433) and the
// bf16 shadow (packed ushort4 stores, channel-minor).
// ---------------------------------------------------------------------------
__global__ __launch_bounds__(256) void corr_kernel(
    const float* __restrict__ A, const float* __restrict__ B2,
    float* __restrict__ feat, unsigned short* __restrict__ fbf)
{
    const int x = threadIdx.x, y = blockIdx.x, b = blockIdx.y;

    float acc[81];
#pragma unroll
    for (int d = 0; d < 81; ++d) acc[d] = 0.f;

    const float* ap = A + ((size_t)b * 96) * HWn + y * Ww + x;
    const float* bp = B2 + ((size_t)b * 96) * HWn;

    for (int c = 0; c < 96; ++c) {
        const float av = ap[(size_t)c * HWn];
        const float* br = bp + (size_t)c * HWn;
#pragma unroll
        for (int dy = -4; dy <= 4; ++dy) {
            const int yy = y + dy;
            const bool yok = (unsigned)yy < 128u;
#pragma unroll
            for (int dx = -4; dx <= 4; ++dx) {
                const int xx = x + dx;
                const float bv = (yok && (unsigned)xx < 256u) ? br[yy * Ww + xx] : 0.f;
                acc[(dy + 4) * 9 + dx + 4] = fmaf(av, bv, acc[(dy + 4) * 9 + dx + 4]);
            }
        }
    }

    float* op = feat + ((size_t)b * FC + 352) * HWn + y * Ww + x;
    unsigned short bv16[81];
#pragma unroll
    for (int d = 0; d < 81; ++d) {
        float v = acc[d];
        v = (v >= 0.f) ? v : 0.1f * v;
        op[(size_t)d * HWn] = v;
        bv16[d] = f2bf(v);
    }
    unsigned short* bq = fbf + ((size_t)(b * Hp + y + 1) * Wp + (x + 1)) * Cp + 352;
#pragma unroll
    for (int k = 0; k < 20; ++k) {
        ushort4 p; p.x = bv16[4*k]; p.y = bv16[4*k+1]; p.z = bv16[4*k+2]; p.w = bv16[4*k+3];
        *(ushort4*)(bq + 4 * k) = p;
    }
    bq[80] = bv16[80];
}

// ---------------------------------------------------------------------------
// MFMA implicit-GEMM 3x3 conv. M=co (weights=A operand), N=pixels (input=B),
// K=ci. Wave = 64 px x (NT*16) co. Reads channel suffix [CS,448) of the bf16
// shadow; CS = 448-CIP. A-frag: lane(co=l&15, ci=quad*8+j) -> 16B from
// Wt[t][co][ci]. B-frag: lane(px=l&15, ci=quad*8+j) -> 16B from shadow.
// D: col(pixel)=l&15, row(co)=quad*4+r  [guide §3, m89/m120 verified].
// FUSE: flow head epilogue (bias + vx/vy weighted mean), no feat write.
// ---------------------------------------------------------------------------
template<int CIP, int NT, bool FUSE>
__global__ __launch_bounds__(256) void conv_mfma(
    const unsigned short* __restrict__ fbf,
    const unsigned short* __restrict__ Wt,     // [9][NT*16][CIP] bf16
    const float* __restrict__ bias,
    float* __restrict__ fout,                  // convs: feat + co_start*HW; flow: flow base
    unsigned short* __restrict__ bfout, int co_start)
{
    constexpr int CS = 448 - CIP;
    const int tid  = threadIdx.x;
    const int lane = tid & 63;
    const int wv   = tid >> 6;
    const int n16  = lane & 15;
    const int quad = lane >> 4;
    const int y = blockIdx.x, b = blockIdx.y;
    const int x0 = wv * 64;

    f32x4 acc[NT][4];
#pragma unroll
    for (int mt = 0; mt < NT; ++mt)
#pragma unroll
        for (int nt = 0; nt < 4; ++nt)
#pragma unroll
            for (int r = 0; r < 4; ++r) acc[mt][nt][r] = 0.f;

    if (!FUSE) {
#pragma unroll
        for (int mt = 0; mt < NT; ++mt) {
            f32x4 bv = *(const f32x4*)(bias + mt * 16 + quad * 4);
#pragma unroll
            for (int nt = 0; nt < 4; ++nt) acc[mt][nt] = bv;
        }
    }

    const unsigned short* fb = fbf + (size_t)b * FB_BATCH;
    const int xb = x0 + n16 + 1;   // padded-x for dx=0

#pragma unroll 1
    for (int ci0 = 0; ci0 < CIP; ci0 += 32) {
#pragma unroll
        for (int tap = 0; tap < 9; ++tap) {
            const int dy = tap / 3 - 1, dx = tap % 3 - 1;
            const unsigned short* bp =
                fb + ((size_t)(y + 1 + dy) * Wp + (xb + dx)) * Cp + (CS + ci0 + quad * 8);
            short8 Bf[4];
#pragma unroll
            for (int nt = 0; nt < 4; ++nt)
                Bf[nt] = *(const short8*)(bp + (size_t)nt * 16 * Cp);

            const unsigned short* apw =
                Wt + ((size_t)tap * (NT * 16) + n16) * CIP + (ci0 + quad * 8);
#pragma unroll
            for (int mt = 0; mt < NT; ++mt) {
                short8 Af = *(const short8*)(apw + (size_t)mt * 16 * CIP);
#pragma unroll
                for (int nt = 0; nt < 4; ++nt)
                    acc[mt][nt] = __builtin_amdgcn_mfma_f32_16x16x32_bf16(
                        Af, Bf[nt], acc[mt][nt], 0, 0, 0);
            }
        }
    }

    if (!FUSE) {
#pragma unroll
        for (int mt = 0; mt < NT; ++mt)
#pragma unroll
            for (int nt = 0; nt < 4; ++nt) {
                const int px = x0 + nt * 16 + n16;
                float* op = fout + ((size_t)b * FC + mt * 16 + quad * 4) * HWn + y * Ww + px;
                unsigned short* bq = bfout +
                    ((size_t)(b * Hp + y + 1) * Wp + (px + 1)) * Cp + co_start + mt * 16 + quad * 4;
                ushort4 pk;
                float v0 = acc[mt][nt][0]; v0 = v0 >= 0.f ? v0 : 0.1f * v0; op[0]       = v0; pk.x = f2bf(v0);
                float v1 = acc[mt][nt][1]; v1 = v1 >= 0.f ? v1 : 0.1f * v1; op[HWn]     = v1; pk.y = f2bf(v1);
                float v2 = acc[mt][nt][2]; v2 = v2 >= 0.f ? v2 : 0.1f * v2; op[2 * HWn] = v2; pk.z = f2bf(v2);
                float v3 = acc[mt][nt][3]; v3 = v3 >= 0.f ? v3 : 0.1f * v3; op[3 * HWn] = v3; pk.w = f2bf(v3);
                *(ushort4*)bq = pk;
            }
    } else {
#pragma unroll
        for (int nt = 0; nt < 4; ++nt) {
            float fx = 0.f, fy = 0.f;
#pragma unroll
            for (int mt = 0; mt < NT; ++mt)
#pragma unroll
                for (int r = 0; r < 4; ++r) {
                    const int co = mt * 16 + quad * 4 + r;
                    if (co < 81) {
                        const float v = acc[mt][nt][r] + bias[co];
                        fx += v * (float)(co % 9 - 4);
                        fy += v * (float)(co / 9 - 4);
                    }
                }
            fx += __shfl_xor(fx, 16, 64); fx += __shfl_xor(fx, 32, 64);
            fy += __shfl_xor(fy, 16, 64); fy += __shfl_xor(fy, 32, 64);
            const int px = x0 + nt * 16 + n16;
            if (quad == 0)      fout[(size_t)b * 2 * HWn + y * Ww + px]       = fx * (1.f / 81.f);
            else if (quad == 1) fout[((size_t)b * 2 + 1) * HWn + y * Ww + px] = fy * (1.f / 81.f);
        }
    }
}

// ---------------------------------------------------------------------------
// d_out = [flow: 4*2*HW] ++ [feat fp32: 4*433*HW].
// d_ws  = [bf16 shadow feat: 120.2 MB] ++ [bf16 weights: 2.2 MB].
// feat channel plan: [c5:0-31][c4:32-95][c3:96-159][c2:160-255][c1:256-351][vol:352-432]
// Each conv reads suffix [CS,448) of the shadow (pad channels are zero).
// ---------------------------------------------------------------------------
extern "C" void kernel_launch(void* const* d_in, const int* in_sizes, int n_in,
                              void* d_out, int out_size, void* d_ws, size_t ws_size,
                              hipStream_t stream)
{
    const float* tenFirst  = (const float*)d_in[0];
    const float* tenSecond = (const float*)d_in[1];
    const float* W1 = (const float*)d_in[2];   const float* b1 = (const float*)d_in[3];
    const float* W2 = (const float*)d_in[4];   const float* b2 = (const float*)d_in[5];
    const float* W3 = (const float*)d_in[6];   const float* b3 = (const float*)d_in[7];
    const float* W4 = (const float*)d_in[8];   const float* b4 = (const float*)d_in[9];
    const float* W5 = (const float*)d_in[10];  const float* b5 = (const float*)d_in[11];
    const float* Wf = (const float*)d_in[12];  const float* bf = (const float*)d_in[13];

    float* out  = (float*)d_out;
    float* feat = out + FLOW_ELEMS;

    unsigned short* fbf   = (unsigned short*)d_ws;
    unsigned short* wbase = fbf + FEATBF_ELEMS;
    const size_t o1 = 0;
    const size_t o2 = o1 + (size_t)9 * 96 * 96;
    const size_t o3 = o2 + (size_t)9 * 96 * 192;
    const size_t o4 = o3 + (size_t)9 * 64 * 288;
    const size_t o5 = o4 + (size_t)9 * 64 * 352;
    const size_t of = o5 + (size_t)9 * 32 * 416;

    // zero shadow (halos + channel pad must be 0 every launch; ws is re-poisoned)
    hipMemsetAsync(d_ws, 0, FEATBF_ELEMS * sizeof(unsigned short), stream);

    auto wt = [&](const float* src, unsigned short* dst, int CO, int CI, int COP, int CIP) {
        int n = 9 * COP * CIP;
        wtrans<<<(n + 255) / 256, 256, 0, stream>>>(src, dst, CO, CI, COP, CIP);
    };
    wt(W1, wbase + o1, 96,  81, 96,  96);
    wt(W2, wbase + o2, 96, 177, 96, 192);
    wt(W3, wbase + o3, 64, 273, 64, 288);
    wt(W4, wbase + o4, 64, 337, 64, 352);
    wt(W5, wbase + o5, 32, 401, 32, 416);
    wt(Wf, wbase + of, 81, 433, 96, 448);

    corr_kernel<<<dim3(Hh, Bn), 256, 0, stream>>>(tenFirst, tenSecond, feat, fbf);

    conv_mfma< 96, 6, false><<<dim3(Hh, Bn), 256, 0, stream>>>(fbf, wbase + o1, b1, feat + (size_t)256 * HWn, fbf, 256);
    conv_mfma<192, 6, false><<<dim3(Hh, Bn), 256, 0, stream>>>(fbf, wbase + o2, b2, feat + (size_t)160 * HWn, fbf, 160);
    conv_mfma<288, 4, false><<<dim3(Hh, Bn), 256, 0, stream>>>(fbf, wbase + o3, b3, feat + (size_t) 96 * HWn, fbf,  96);
    conv_mfma<352, 4, false><<<dim3(Hh, Bn), 256, 0, stream>>>(fbf, wbase + o4, b4, feat + (size_t) 32 * HWn, fbf,  32);
    conv_mfma<416, 2, false><<<dim3(Hh, Bn), 256, 0, stream>>>(fbf, wbase + o5, b5, feat,                     fbf,   0);
    conv_mfma<448, 6, true ><<<dim3(Hh, Bn), 256, 0, stream>>>(fbf, wbase + of, bf, out,                  nullptr,   0);
}